// Round 4
// baseline (156.064 us; speedup 1.0000x reference)
//
#include <hip/hip_runtime.h>

#define MDIM 2048   // B
#define KD   2560   // HEAD
#define NHID 2048   // N_HID
#define INF  512
#define NTOT 10240  // 5*NHID
#define NS   40     // K-steps of 64

typedef __attribute__((ext_vector_type(16))) float f32x16;
typedef __attribute__((ext_vector_type(8))) short short8;
typedef __attribute__((ext_vector_type(8))) unsigned short ushort8v;
typedef __attribute__((ext_vector_type(4))) unsigned short ushort4v;

#define AS1 __attribute__((address_space(1)))
#define AS3 __attribute__((address_space(3)))

__device__ __forceinline__ unsigned short f2bf(float f) {
    unsigned u = __float_as_uint(f);
    u += 0x7fffu + ((u >> 16) & 1u);
    return (unsigned short)(u >> 16);
}
__device__ __forceinline__ float bf2f(unsigned short s) {
    return __uint_as_float(((unsigned)s) << 16);
}

// ---------------- prep: xc = concat(x, hidden) -> bf16 [MDIM][KD] ----------------
__global__ void prep_xc(const float* __restrict__ x, const float* __restrict__ h,
                        unsigned short* __restrict__ xc) {
    int idx = blockIdx.x * 256 + threadIdx.x;
    int e = idx * 8;
    int b = e / KD;
    int c = e - b * KD;
    const float* src = (c < INF) ? (x + (size_t)b * INF + c)
                                 : (h + (size_t)b * NHID + (c - INF));
    float4 v0 = *(const float4*)src;
    float4 v1 = *(const float4*)(src + 4);
    ushort8v o;
    o[0] = f2bf(v0.x); o[1] = f2bf(v0.y); o[2] = f2bf(v0.z); o[3] = f2bf(v0.w);
    o[4] = f2bf(v1.x); o[5] = f2bf(v1.y); o[6] = f2bf(v1.z); o[7] = f2bf(v1.w);
    *(ushort8v*)(xc + e) = o;
}

// ---------------- prep: Wm[k] = W_k * mask -> bf16, 5 planes = [NTOT][KD] ----------------
__global__ void prep_wm(const float* __restrict__ Wg, const float* __restrict__ Wh,
                        const float* __restrict__ Wfg, const float* __restrict__ Wfh,
                        const float* __restrict__ Wp, const float* __restrict__ mask,
                        unsigned short* __restrict__ Wm) {
    int idx = blockIdx.x * 256 + threadIdx.x;
    size_t e = (size_t)idx * 4;
    const size_t PL = (size_t)NHID * KD;
    float4 m = *(const float4*)(mask + e);
    const float* Ws[5] = {Wg, Wh, Wfg, Wfh, Wp};
    #pragma unroll
    for (int k = 0; k < 5; ++k) {
        float4 w = *(const float4*)(Ws[k] + e);
        ushort4v o;
        o[0] = f2bf(w.x * m.x); o[1] = f2bf(w.y * m.y);
        o[2] = f2bf(w.z * m.z); o[3] = f2bf(w.w * m.w);
        *(ushort4v*)(Wm + k * PL + e) = o;
    }
}

// ---------------- GEMM: C[2048][10240] = A (2048xK) . B^T (10240xK) ----------------
// 32x32x16 MFMA. BM=256 BN=320 BK=64, 8 waves (4M x 2N), per-wave 64x160.
// grid 32x8 = 256 blocks = 1/CU, zero tail. LDS double-buffered 144KB.
// ONE barrier per K-step: all staging for kt+1 targets the opposite buffer,
// issued at top of kt, drained by vmcnt(0) at the boundary (in flight the
// whole step -> wait is ~free). No mid-step barriers: waves counter-phase so
// LDS reads overlap MFMA. XOR swizzle slot^=(row&7) via pre-swizzled source.
#define MFMA32(d, va, vb) d = __builtin_amdgcn_mfma_f32_32x32x16_bf16(va, vb, d, 0, 0, 0)

__global__ __launch_bounds__(512, 2) void gemm32(
    const unsigned short* __restrict__ A,
    const unsigned short* __restrict__ B,
    unsigned short* __restrict__ C) {
    __shared__ unsigned short lsA[2][256 * 64];   // 64 KB
    __shared__ unsigned short lsB[2][320 * 64];   // 80 KB

    const int tid  = threadIdx.x;
    const int lane = tid & 63;
    const int w    = tid >> 6;       // 0..7
    const int wm   = w >> 1;         // 0..3  (M waves)
    const int wn   = w & 1;          // 0..1  (N waves)
    const int l31  = lane & 31;
    const int hi   = lane >> 5;      // 0..1
    const int l7   = lane & 7;
    const int m0   = blockIdx.y * 256;
    const int n0   = blockIdx.x * 320;

    const unsigned short* gA = A + (size_t)m0 * KD;
    const unsigned short* gB = B + (size_t)n0 * KD;
    // staging: per-lane source offset, 8 rows x 8 slots, slot pre-swizzled by row&7
    const int soff = (lane >> 3) * KD + (((lane & 7) ^ (lane >> 3)) << 3);
    const int ar0 = (w >> 2) * 128 + (w & 3) * 8;   // + 32*j, j=0..3
    const int br0 = (w >> 1) * 80 + (w & 1) * 8;    // + 16*j, j=0..4

#define SA(j, t, b) __builtin_amdgcn_global_load_lds( \
        (const AS1 unsigned int*)(gA + (size_t)(ar0 + 32 * (j)) * KD + (t) * 64 + soff), \
        (AS3 unsigned int*)(&lsA[b][(ar0 + 32 * (j)) * 64]), 16, 0, 0)
#define SB(j, t, b) __builtin_amdgcn_global_load_lds( \
        (const AS1 unsigned int*)(gB + (size_t)(br0 + 16 * (j)) * KD + (t) * 64 + soff), \
        (AS3 unsigned int*)(&lsB[b][(br0 + 16 * (j)) * 64]), 16, 0, 0)

    // fragment read bases (ushort index): row*64 + swizzled-slot*8
    const int arow = wm * 64 + l31;   // + 32*m
    const int brow = wn * 160 + l31;  // + 32*n

    f32x16 acc[2][5] = {};

    // prologue: stage kt=0 into buf 0
    SA(0, 0, 0); SA(1, 0, 0); SA(2, 0, 0); SA(3, 0, 0);
    SB(0, 0, 0); SB(1, 0, 0); SB(2, 0, 0); SB(3, 0, 0); SB(4, 0, 0);
    asm volatile("s_waitcnt vmcnt(0)" ::: "memory");
    __builtin_amdgcn_s_barrier();

    for (int kt = 0; kt < NS; ++kt) {
        const int bc = kt & 1, bo = bc ^ 1;
        // stage kt+1 into the opposite buffer (not read this step)
        if (kt < NS - 1) {
            SA(0, kt + 1, bo); SA(1, kt + 1, bo); SA(2, kt + 1, bo); SA(3, kt + 1, bo);
            SB(0, kt + 1, bo); SB(1, kt + 1, bo); SB(2, kt + 1, bo); SB(3, kt + 1, bo); SB(4, kt + 1, bo);
        }
        // 4 k-subtiles of 16; compiler software-pipelines reads into MFMA
        #pragma unroll
        for (int s = 0; s < 4; ++s) {
            const int cs = (((2 * s + hi) ^ l7) << 3);
            short8 av[2], bv[5];
            #pragma unroll
            for (int m = 0; m < 2; ++m)
                av[m] = *(const short8*)&lsA[bc][(arow + 32 * m) * 64 + cs];
            #pragma unroll
            for (int n = 0; n < 5; ++n)
                bv[n] = *(const short8*)&lsB[bc][(brow + 32 * n) * 64 + cs];
            __builtin_amdgcn_s_setprio(1);
            #pragma unroll
            for (int m = 0; m < 2; ++m)
                #pragma unroll
                for (int n = 0; n < 5; ++n)
                    MFMA32(acc[m][n], av[m], bv[n]);
            __builtin_amdgcn_s_setprio(0);
        }
        // boundary: own staging loads drained (issued a full K-step ago), then
        // all waves synced before kt+1 (whose staging overwrites buf bc at kt+1 top)
        asm volatile("s_waitcnt vmcnt(0)" ::: "memory");
        __builtin_amdgcn_s_barrier();
    }

    // C/D layout (32x32): col = lane&31, row = (reg&3) + 8*(reg>>2) + 4*hi
    #pragma unroll
    for (int m = 0; m < 2; ++m) {
        #pragma unroll
        for (int n = 0; n < 5; ++n) {
            int col = n0 + wn * 160 + n * 32 + l31;
            #pragma unroll
            for (int q = 0; q < 4; ++q) {
                int row = m0 + wm * 64 + m * 32 + q * 8 + 4 * hi;
                #pragma unroll
                for (int t = 0; t < 4; ++t)
                    C[(size_t)(row + t) * NTOT + col] = f2bf(acc[m][n][q * 4 + t]);
            }
        }
    }
#undef SA
#undef SB
}

// ---------------- epilogue: activations + mix -> y_pred, new_hidden (f32) ----------------
__global__ void epilogue(const unsigned short* __restrict__ C,
                         const float* __restrict__ bg, const float* __restrict__ bh,
                         const float* __restrict__ bfg, const float* __restrict__ bfh,
                         const float* __restrict__ bp,
                         float* __restrict__ out) {
    int idx = blockIdx.x * 256 + threadIdx.x;
    size_t e = (size_t)idx * 8;
    int b = (int)(e >> 11);
    int o = (int)(e & (NHID - 1));
    const size_t PL = (size_t)MDIM * NHID;
    const unsigned short* row = C + (size_t)b * NTOT + o;

    ushort8v vg  = *(const ushort8v*)(row + 0 * NHID);
    ushort8v vh  = *(const ushort8v*)(row + 1 * NHID);
    ushort8v vfg = *(const ushort8v*)(row + 2 * NHID);
    ushort8v vfh = *(const ushort8v*)(row + 3 * NHID);
    ushort8v vp  = *(const ushort8v*)(row + 4 * NHID);

    float bgv[8], bhv[8], bfgv[8], bfhv[8], bpv[8];
    *(float4*)bgv  = *(const float4*)(bg + o);  *(float4*)(bgv + 4)  = *(const float4*)(bg + o + 4);
    *(float4*)bhv  = *(const float4*)(bh + o);  *(float4*)(bhv + 4)  = *(const float4*)(bh + o + 4);
    *(float4*)bfgv = *(const float4*)(bfg + o); *(float4*)(bfgv + 4) = *(const float4*)(bfg + o + 4);
    *(float4*)bfhv = *(const float4*)(bfh + o); *(float4*)(bfhv + 4) = *(const float4*)(bfh + o + 4);
    *(float4*)bpv  = *(const float4*)(bp + o);  *(float4*)(bpv + 4)  = *(const float4*)(bp + o + 4);

    float yv[8], nhv[8];
    #pragma unroll
    for (int j = 0; j < 8; ++j) {
        float g    = tanhf(bf2f(vg[j]) + bgv[j]);
        float hh   = tanhf(bf2f(vh[j]) + bhv[j]);
        float s    = bf2f(vfg[j]) + bfgv[j] + bf2f(vfh[j]) + bfhv[j];
        float gate = 1.0f / (1.0f + __expf(-s));
        float nh   = g * (1.0f - gate) + gate * hh;
        nhv[j] = nh;
        yv[j]  = bf2f(vp[j]) + bpv[j] + nh;
    }
    *(float4*)(out + e)          = *(float4*)yv;
    *(float4*)(out + e + 4)      = *(float4*)(yv + 4);
    *(float4*)(out + PL + e)     = *(float4*)nhv;
    *(float4*)(out + PL + e + 4) = *(float4*)(nhv + 4);
}

extern "C" void kernel_launch(void* const* d_in, const int* in_sizes, int n_in,
                              void* d_out, int out_size, void* d_ws, size_t ws_size,
                              hipStream_t stream) {
    const float* x      = (const float*)d_in[0];
    const float* hidden = (const float*)d_in[1];
    const float* mask   = (const float*)d_in[2];
    const float* Wg     = (const float*)d_in[3];
    const float* bg     = (const float*)d_in[4];
    const float* Wh     = (const float*)d_in[5];
    const float* bh     = (const float*)d_in[6];
    const float* Wfg    = (const float*)d_in[7];
    const float* bfg    = (const float*)d_in[8];
    const float* Wfh    = (const float*)d_in[9];
    const float* bfh    = (const float*)d_in[10];
    const float* Wp     = (const float*)d_in[11];
    const float* bp     = (const float*)d_in[12];
    float* out = (float*)d_out;

    const size_t need = (size_t)MDIM * KD * 2 + (size_t)NTOT * KD * 2
                      + (size_t)MDIM * NTOT * 2;
    if (ws_size < need) return;

    unsigned short* xc = (unsigned short*)d_ws;
    unsigned short* Wm = xc + (size_t)MDIM * KD;
    unsigned short* C  = Wm + (size_t)NTOT * KD;

    prep_xc<<<MDIM * KD / 8 / 256, 256, 0, stream>>>(x, hidden, xc);
    prep_wm<<<NHID * KD / 4 / 256, 256, 0, stream>>>(Wg, Wh, Wfg, Wfh, Wp, mask, Wm);
    dim3 grid(NTOT / 320, MDIM / 256);
    gemm32<<<grid, 512, 0, stream>>>(xc, Wm, C);
    epilogue<<<MDIM * NHID / 8 / 256, 256, 0, stream>>>(C, bg, bh, bfg, bfh, bp, out);
}